// Round 8
// baseline (189.710 us; speedup 1.0000x reference)
//
#include <hip/hip_runtime.h>

// QuantizedConv2d: x(16,128,112,112) fp32, packed uint8-pair weights.
// Fast path: pre-dequant weights (bf16, GLL-linear layout) + pre-transpose x to
// padded CHANNEL-OCTET-PLANE bf16 layout xp[n][oct=c>>3][114][114][8ch] in d_ws,
// then implicit-GEMM conv (9 shifted GEMMs) with mfma_f32_16x16x32_bf16.
// R16 = R14 (verified 129us conv: BM=256 x BN=128, 8 waves 64x64, 3-buffer
// 72 KB pipeline, 2 blocks/CU, coalesced octet-plane B, XCD swizzle) with the
// K-loop sync slimmed: the leading barrier per K-step is provably redundant
// (stage target sbuf's readers finished before the PREVIOUS end-barrier) and
// the forced lgkmcnt(0) drain is replaced by compiler-scheduled counted lgkm
// waits -> ONE barrier + vmcnt(3) per K-step, MFMAs start on first fragment.
// Pre-passes: dequant + zero_border fused into one launch.
// Fallback to round-1 kernels if ws_size too small.

#define C_IN  128
#define H_IN  112
#define W_IN  112
#define HW    (H_IN * W_IN)       // 12544
#define N_B   16
#define O_C   256
#define P_TOT (N_B * HW)          // 200704

#define HP    114                 // padded H/W
#define PLANE (HP * HP * 8)       // shorts per (n,oct) plane = 103968
#define XP_OFF   (1u << 20)       // x_p offset in ws (Wd lives at 0)
#define XP_BYTES (16u * 16u * 114u * 114u * 8u * 2u)   // 53,231,616
#define WS_NEED  (XP_OFF + XP_BYTES)

#define DQ_N      (O_C * C_IN * 9 / 2)     // 147456 dequant items
#define DQ_BLK    ((DQ_N + 255) / 256)     // 576 blocks
#define ZB_N      (N_B * 16 * 452)         // 115712 border items
#define ZB_BLK    ((ZB_N + 255) / 256)     // 452 blocks

typedef __attribute__((ext_vector_type(8))) short bhalf8;
typedef __attribute__((ext_vector_type(4))) float floatx4;

__device__ __forceinline__ unsigned short f2bf(float f) {
  union { float f; unsigned u; } v; v.f = f;
  return (unsigned short)((v.u + 0x7FFFu + ((v.u >> 16) & 1u)) >> 16);  // RTN-even
}

#define GLL16(srcp, ldsp)                                                     \
  __builtin_amdgcn_global_load_lds(                                           \
      (const __attribute__((address_space(1))) unsigned int*)(srcp),          \
      (__attribute__((address_space(3))) unsigned int*)(ldsp), 16, 0, 0)

// ---------------- fast-path pre-passes ----------------

// Fused: dequant (blocks [0,576)) + xp border zeroing (blocks [576,1028)).
// Wd layout: [r][q'=c>>3][o][c&7] -> flat ((r*16 + (c>>3))*256 + o)*8 + (c&7)
__global__ void prep_fast(const float* __restrict__ pw,
                          const float* __restrict__ scale_p,
                          const float* __restrict__ zp_p,
                          unsigned short* __restrict__ Wd,
                          unsigned short* __restrict__ xp) {
  if (blockIdx.x < DQ_BLK) {
    int i = blockIdx.x * 256 + threadIdx.x;
    if (i >= DQ_N) return;
    float p = pw[i];
    float s = scale_p[0], z = zp_p[0];
    float q1 = floorf(p);
    float q2 = rintf((p - q1) * 255.0f);
    q2 = fminf(fmaxf(q2, 0.0f), 255.0f);
    float wv[2] = { q1 * s + z, q2 * s + z };
#pragma unroll
    for (int k = 0; k < 2; ++k) {
      int f = 2 * i + k;
      int o = f / 1152;
      int rem = f - o * 1152;
      int c = rem / 9;
      int r = rem - c * 9;
      Wd[((r * 16 + (c >> 3)) * 256 + o) * 8 + (c & 7)] = f2bf(wv[k]);
    }
  } else {
    int idx = (blockIdx.x - DQ_BLK) * 256 + threadIdx.x;
    if (idx >= ZB_N) return;
    int n    = idx / (16 * 452);
    int rem  = idx - n * (16 * 452);
    int oct  = rem / 452;
    int b    = rem - oct * 452;
    int h, w;
    if      (b < 114) { h = 0;           w = b; }
    else if (b < 228) { h = 113;         w = b - 114; }
    else if (b < 340) { h = b - 228 + 1; w = 0; }
    else              { h = b - 340 + 1; w = 113; }
    bhalf8 z = {0, 0, 0, 0, 0, 0, 0, 0};
    *(bhalf8*)(xp + ((size_t)(n * 16 + oct) * HP + h) * HP * 8 + (size_t)w * 8) = z;
  }
}

// NCHW fp32 -> padded octet-plane bf16 (interior only). Block = (s, h, n).
__global__ void pad_kernel(const float* __restrict__ x,
                           unsigned short* __restrict__ xp) {
  __shared__ unsigned short sh[128][60];   // [c][w_local]
  const int tid = threadIdx.x;
  const int s = blockIdx.x;    // 0..1
  const int h = blockIdx.y;    // 0..111
  const int n = blockIdx.z;    // 0..15
  const int w0 = s * 56;

#pragma unroll
  for (int k = 0; k < 7; ++k) {
    int idx = tid + 256 * k;               // < 1792 = 128c * 14wq
    int c = idx / 14;
    int wq = idx - c * 14;
    const float* src = x + (size_t)(n * 128 + c) * HW + h * W_IN + w0 + wq * 4;
    float4 v = *(const float4*)src;
    ushort4 b;
    b.x = f2bf(v.x); b.y = f2bf(v.y); b.z = f2bf(v.z); b.w = f2bf(v.w);
    *(ushort4*)&sh[c][wq * 4] = b;
  }
  __syncthreads();
  // write: 896 = 16 oct x 56 wl items; wl fastest across threads -> 16B-contig
#pragma unroll
  for (int k = 0; k < 4; ++k) {
    int idx = tid + 256 * k;
    if (idx < 896) {
      int oct = idx / 56;
      int wl  = idx - oct * 56;
      bhalf8 v;
#pragma unroll
      for (int j = 0; j < 8; ++j) v[j] = (short)sh[oct * 8 + j][wl];
      unsigned short* dst = xp +
          ((size_t)(n * 16 + oct) * HP + (h + 1)) * HP * 8 +
          (size_t)(w0 + wl + 1) * 8;
      *(bhalf8*)dst = v;
    }
  }
}

// --- fast conv: BM=256 (all O), BN=128 px, BK=32, 8 waves, wave tile 64x64 ---
// 3-deep LDS pipeline, ONE barrier + counted vmcnt(3) per K-step, compiler-
// scheduled lgkm waits, setprio. Coalesced octet-plane B staging.

__global__ __launch_bounds__(512, 2) void conv_fast(
    const unsigned short* __restrict__ xp,   // octet-plane padded bf16
    const unsigned short* __restrict__ Wd,   // [9][16][256][8] bf16
    const float* __restrict__ bias,
    float* __restrict__ out)
{
  __shared__ unsigned short As[3 * 4 * 256 * 8];   // 3 x 16 KB (slab 8192 shorts)
  __shared__ unsigned short Bs[3 * 4 * 128 * 8];   // 3 x  8 KB (slab 4096 shorts)

  const int tid  = threadIdx.x;
  const int lane = tid & 63;
  const int wave = tid >> 6;       // 0..7
  const int wm   = wave >> 1;      // 0..3 -> 64 o each
  const int wn   = wave & 1;       // 0..1 -> 64 px each
  const int lr   = lane >> 4;      // k-quarter
  const int lc   = lane & 15;

  // bijective XCD swizzle: 1568 blocks = 8 XCDs x 196
  const int bswz = (blockIdx.x & 7) * 196 + (blockIdx.x >> 3);
  const int p0  = bswz * 128;
  const int n   = p0 / HW;         // exact: 12544 % 128 == 0
  const int hw0 = p0 - n * HW;

  // B staging: thread t <-> (oct_lo = t>>7, px = t&127); LDS = t*16B (linear).
  // Per-lane stride = 16B -> fully coalesced (1 KB contiguous per wave).
  const int pp  = tid & 127;
  const int hwp = hw0 + pp;
  const int h   = hwp / W_IN;
  const int w   = hwp - h * W_IN;
  const unsigned short* bsrc =
      xp + ((size_t)(n * 16 + (tid >> 7)) * HP + (h + 1)) * HP * 8 +
      (size_t)(w + 1) * 8;

  // A staging: thread t covers shorts t*8 of a 4096-short half-slab (+4096 2nd GLL)
  const unsigned short* asrc = Wd + tid * 8;

  // wave-uniform LDS dest bases (lane*16B added by HW)
  unsigned short* adst = As + wave * 512;
  unsigned short* bdst = Bs + wave * 512;

  // fragment read bases
  const unsigned short* arow = As + lr * 2048 + (wm * 64 + lc) * 8;
  const unsigned short* brow = Bs + lr * 1024 + (wn * 64 + lc) * 8;

  floatx4 acc[4][4];
#pragma unroll
  for (int a = 0; a < 4; ++a)
#pragma unroll
    for (int b = 0; b < 4; ++b)
      acc[a][b] = (floatx4){0.f, 0.f, 0.f, 0.f};

  auto stageA = [&](int t, int buf) {
    int r = t >> 2, q4 = t & 3;
    const unsigned short* s = asrc + (r * 16 + q4 * 4) * 2048;
    GLL16(s,        adst + buf * 8192);
    GLL16(s + 4096, adst + buf * 8192 + 4096);
  };
  auto stageB = [&](int t, int buf) {
    int r = t >> 2, q4 = t & 3;
    int dh = r / 3, dw = r - dh * 3;             // 0..2
    // wave-uniform: octet-plane step (q4*4 planes) + tap shift within plane
    ptrdiff_t off = (ptrdiff_t)(q4 * 4) * PLANE +
                    (ptrdiff_t)((dh - 1) * HP + (dw - 1)) * 8;
    GLL16(bsrc + off, bdst + buf * 4096);
  };

  // prologue: stage K-steps 0,1
  stageA(0, 0); stageB(0, 0);
  stageA(1, 1); stageB(1, 1);
  asm volatile("s_waitcnt vmcnt(3)" ::: "memory");   // step-0 tile landed
  __builtin_amdgcn_s_barrier();

  int buf = 0;
  for (int kt = 0; kt < 34; ++kt) {                  // last 2 K-steps peeled
    int sbuf = buf + 2; if (sbuf >= 3) sbuf -= 3;
    const unsigned short* ar = arow + buf * 8192;
    const unsigned short* br = brow + buf * 4096;
    bhalf8 af[4], bfv[4];

    // issue next-tile staging first (VMEM), then this tile's fragment reads
    // (LDS); compiler inserts counted lgkm waits so MFMAs start on the first
    // landed fragment. sbuf's last readers finished before the PREVIOUS
    // end-barrier (collective), so no leading barrier is needed.
    stageA(kt + 2, sbuf);
    stageB(kt + 2, sbuf);
#pragma unroll
    for (int mi = 0; mi < 4; ++mi) af[mi] = *(const bhalf8*)(ar + mi * 128);
#pragma unroll
    for (int ni = 0; ni < 4; ++ni) bfv[ni] = *(const bhalf8*)(br + ni * 128);
    __builtin_amdgcn_s_setprio(1);
#pragma unroll
    for (int mi = 0; mi < 4; ++mi)
#pragma unroll
      for (int ni = 0; ni < 4; ++ni)
        acc[mi][ni] = __builtin_amdgcn_mfma_f32_16x16x32_bf16(
            af[mi], bfv[ni], acc[mi][ni], 0, 0, 0);
    __builtin_amdgcn_s_setprio(0);
    // counted wait: leaves only kt+2's 3 loads outstanding -> kt+1 tile landed
    // (own-wave vmcnt + collective barrier = cross-wave LDS visibility)
    asm volatile("s_waitcnt vmcnt(3)" ::: "memory");
    __builtin_amdgcn_s_barrier();

    buf = (buf + 1 == 3) ? 0 : buf + 1;
  }

  // epilogue K-steps 34,35: fully staged; drain once, no more barriers
  asm volatile("s_waitcnt vmcnt(0)" ::: "memory");
  __builtin_amdgcn_s_barrier();
#pragma unroll
  for (int kk = 0; kk < 2; ++kk) {
    int b2 = (34 + kk) % 3;
    const unsigned short* ar = arow + b2 * 8192;
    const unsigned short* br = brow + b2 * 4096;
    bhalf8 af[4], bfv[4];
#pragma unroll
    for (int mi = 0; mi < 4; ++mi) af[mi]  = *(const bhalf8*)(ar + mi * 128);
#pragma unroll
    for (int ni = 0; ni < 4; ++ni) bfv[ni] = *(const bhalf8*)(br + ni * 128);
#pragma unroll
    for (int mi = 0; mi < 4; ++mi)
#pragma unroll
      for (int ni = 0; ni < 4; ++ni)
        acc[mi][ni] = __builtin_amdgcn_mfma_f32_16x16x32_bf16(
            af[mi], bfv[ni], acc[mi][ni], 0, 0, 0);
  }

  // C-write: D col = lc (pixel), row = lr*4+j (o)
#pragma unroll
  for (int mi = 0; mi < 4; ++mi) {
#pragma unroll
    for (int j = 0; j < 4; ++j) {
      const int o  = wm * 64 + mi * 16 + lr * 4 + j;
      const float bo = bias[o];
      float* orow = out + ((size_t)(n * O_C + o)) * HW + hw0 + wn * 64;
#pragma unroll
      for (int ni = 0; ni < 4; ++ni)
        orow[ni * 16 + lc] = acc[mi][ni][j] + bo;
    }
  }
}

// ---------------- fallback (round-1, verified) ----------------

__global__ void dequant_kernel(const float* __restrict__ pw,
                               const float* __restrict__ scale_p,
                               const float* __restrict__ zp_p,
                               unsigned short* __restrict__ Wd) {
  int i = blockIdx.x * 256 + threadIdx.x;
  if (i >= (O_C * C_IN * 9) / 2) return;
  float p = pw[i];
  float s = scale_p[0], z = zp_p[0];
  float q1 = floorf(p);
  float q2 = rintf((p - q1) * 255.0f);
  q2 = fminf(fmaxf(q2, 0.0f), 255.0f);
  float wv[2] = { q1 * s + z, q2 * s + z };
#pragma unroll
  for (int k = 0; k < 2; ++k) {
    int f = 2 * i + k;
    int o = f / 1152;
    int rem = f - o * 1152;
    int c = rem / 9;
    int r = rem - c * 9;
    Wd[(r * O_C + o) * C_IN + c] = f2bf(wv[k]);
  }
}

__global__ __launch_bounds__(256, 2) void conv_kernel(
    const float* __restrict__ x,
    const unsigned short* __restrict__ Wd,
    const float* __restrict__ bias,
    float* __restrict__ out)
{
  __shared__ unsigned short As[128][32];
  __shared__ unsigned short Bs[4][128][8];
  const int tid  = threadIdx.x;
  const int lane = tid & 63;
  const int wave = tid >> 6;
  const int wm   = wave >> 1;
  const int wn   = wave & 1;
  const int p0   = blockIdx.x * 128;
  const int o0   = blockIdx.y * 128;
  const int n    = p0 / HW;
  const int hw0  = p0 - n * HW;
  const int pp = tid & 127;
  const int qh = tid >> 7;
  const int hwp = hw0 + pp;
  const int h  = hwp / W_IN;
  const int w  = hwp - h * W_IN;
  const int xnbase = n * C_IN * HW;
  const int lr = lane >> 4;
  const int lc = lane & 15;
  floatx4 acc[4][4];
#pragma unroll
  for (int a = 0; a < 4; ++a)
#pragma unroll
    for (int b = 0; b < 4; ++b)
      acc[a][b] = (floatx4){0.f, 0.f, 0.f, 0.f};
  for (int r = 0; r < 9; ++r) {
    const int dh = r / 3 - 1;
    const int dw = r % 3 - 1;
    const int ih = h + dh;
    const int iw = w + dw;
    const bool valid = ((unsigned)ih < (unsigned)H_IN) & ((unsigned)iw < (unsigned)W_IN);
    const int xb = xnbase + ih * W_IN + iw;
    const unsigned short* Wr = Wd + r * (O_C * C_IN);
    for (int c0 = 0; c0 < C_IN; c0 += 32) {
      __syncthreads();
#pragma unroll
      for (int j = 0; j < 2; ++j) {
        int sdx  = tid + 256 * j;
        int oo = sdx >> 2;
        int c8 = (sdx & 3) << 3;
        bhalf8 v = *(const bhalf8*)(Wr + (o0 + oo) * C_IN + c0 + c8);
        *(bhalf8*)(&As[oo][c8]) = v;
      }
#pragma unroll
      for (int j = 0; j < 2; ++j) {
        int q = qh + 2 * j;
        bhalf8 v;
        if (valid) {
          const float* xpp = x + xb + (c0 + (q << 3)) * HW;
#pragma unroll
          for (int i = 0; i < 8; ++i) v[i] = (short)f2bf(xpp[i * HW]);
        } else {
#pragma unroll
          for (int i = 0; i < 8; ++i) v[i] = 0;
        }
        *(bhalf8*)(&Bs[q][pp][0]) = v;
      }
      __syncthreads();
      bhalf8 af[4], bfv[4];
#pragma unroll
      for (int mi = 0; mi < 4; ++mi)
        af[mi] = *(const bhalf8*)(&As[wm * 64 + mi * 16 + lc][lr << 3]);
#pragma unroll
      for (int ni = 0; ni < 4; ++ni)
        bfv[ni] = *(const bhalf8*)(&Bs[lr][wn * 64 + ni * 16 + lc][0]);
#pragma unroll
      for (int mi = 0; mi < 4; ++mi)
#pragma unroll
        for (int ni = 0; ni < 4; ++ni)
          acc[mi][ni] = __builtin_amdgcn_mfma_f32_16x16x32_bf16(
              af[mi], bfv[ni], acc[mi][ni], 0, 0, 0);
    }
  }
#pragma unroll
  for (int mi = 0; mi < 4; ++mi) {
#pragma unroll
    for (int j = 0; j < 4; ++j) {
      const int o  = o0 + wm * 64 + mi * 16 + lr * 4 + j;
      const float bo = bias[o];
      float* orow = out + (n * O_C + o) * HW + hw0 + wn * 64;
#pragma unroll
      for (int ni = 0; ni < 4; ++ni)
        orow[ni * 16 + lc] = acc[mi][ni][j] + bo;
    }
  }
}

// ---------------- launch ----------------

extern "C" void kernel_launch(void* const* d_in, const int* in_sizes, int n_in,
                              void* d_out, int out_size, void* d_ws, size_t ws_size,
                              hipStream_t stream) {
  const float* x    = (const float*)d_in[0];
  const float* pw   = (const float*)d_in[1];
  const float* sw   = (const float*)d_in[2];
  const float* zp   = (const float*)d_in[3];
  const float* bias = (const float*)d_in[4];
  float* out = (float*)d_out;
  unsigned short* Wd = (unsigned short*)d_ws;

  if (ws_size >= WS_NEED) {
    unsigned short* xp = (unsigned short*)((char*)d_ws + XP_OFF);
    prep_fast<<<dim3(DQ_BLK + ZB_BLK), dim3(256), 0, stream>>>(pw, sw, zp, Wd, xp);
    pad_kernel<<<dim3(2, H_IN, N_B), dim3(256), 0, stream>>>(x, xp);
    conv_fast<<<dim3(P_TOT / 128), dim3(512), 0, stream>>>(xp, Wd, bias, out);
  } else {
    dequant_kernel<<<dim3((O_C * C_IN * 9 / 2 + 255) / 256), dim3(256), 0, stream>>>(
        pw, sw, zp, Wd);
    dim3 grid(P_TOT / 128, O_C / 128);
    conv_kernel<<<grid, dim3(256), 0, stream>>>(x, Wd, bias, out);
  }
}

// Round 9
// 158.511 us; speedup vs baseline: 1.1968x; 1.1968x over previous
//
#include <hip/hip_runtime.h>

// QuantizedConv2d: x(16,128,112,112) fp32, packed uint8-pair weights.
// Fast path (R17): ONE fused pre-pass launch (dequant Wd + xp border zero +
// NCHW->octet-plane pad transpose, disjoint writes, block-range dispatch),
// then the VERIFIED R14 conv (129us): implicit-GEMM, BM=256 x BN=128, 8 waves
// 64x64, 3-buffer 72 KB pipeline, 2 blocks/CU, 16 MFMA per barrier-pair,
// counted vmcnt(3), setprio, XCD swizzle, coalesced octet-plane B staging.
// R14's K-loop sync structure is FROZEN (R9/R11/R15/R16 all regressed it).
// Fallback to round-1 kernels if ws_size too small.

#define C_IN  128
#define H_IN  112
#define W_IN  112
#define HW    (H_IN * W_IN)       // 12544
#define N_B   16
#define O_C   256
#define P_TOT (N_B * HW)          // 200704

#define HP    114                 // padded H/W
#define PLANE (HP * HP * 8)       // shorts per (n,oct) plane = 103968
#define XP_OFF   (1u << 20)       // x_p offset in ws (Wd lives at 0)
#define XP_BYTES (16u * 16u * 114u * 114u * 8u * 2u)   // 53,231,616
#define WS_NEED  (XP_OFF + XP_BYTES)

#define DQ_N      (O_C * C_IN * 9 / 2)     // 147456 dequant items
#define DQ_BLK    ((DQ_N + 255) / 256)     // 576 blocks
#define ZB_N      (N_B * 16 * 452)         // 115712 border items
#define ZB_BLK    ((ZB_N + 255) / 256)     // 452 blocks
#define PAD_BLK   (2 * H_IN * N_B)         // 3584 blocks
#define PREP_BLK  (DQ_BLK + ZB_BLK + PAD_BLK)   // 4612

typedef __attribute__((ext_vector_type(8))) short bhalf8;
typedef __attribute__((ext_vector_type(4))) float floatx4;

__device__ __forceinline__ unsigned short f2bf(float f) {
  union { float f; unsigned u; } v; v.f = f;
  return (unsigned short)((v.u + 0x7FFFu + ((v.u >> 16) & 1u)) >> 16);  // RTN-even
}

#define GLL16(srcp, ldsp)                                                     \
  __builtin_amdgcn_global_load_lds(                                           \
      (const __attribute__((address_space(1))) unsigned int*)(srcp),          \
      (__attribute__((address_space(3))) unsigned int*)(ldsp), 16, 0, 0)

// ---------------- fused fast-path pre-pass ----------------
// blocks [0, DQ_BLK):           dequant weights -> Wd (GLL-linear layout)
// blocks [DQ_BLK, +ZB_BLK):     zero 1-px border of every (n,oct) xp plane
// blocks [DQ_BLK+ZB_BLK, end):  NCHW fp32 -> padded octet-plane bf16 interior
// All writes disjoint; all must simply precede conv_fast.

__global__ void prep_all(const float* __restrict__ pw,
                         const float* __restrict__ scale_p,
                         const float* __restrict__ zp_p,
                         const float* __restrict__ x,
                         unsigned short* __restrict__ Wd,
                         unsigned short* __restrict__ xp) {
  __shared__ unsigned short sh[128][60];   // used by pad branch only
  const int bx  = blockIdx.x;
  const int tid = threadIdx.x;

  if (bx < DQ_BLK) {
    // ---- dequant: Wd[((r*16 + (c>>3))*256 + o)*8 + (c&7)] ----
    int i = bx * 256 + tid;
    if (i >= DQ_N) return;
    float p = pw[i];
    float s = scale_p[0], z = zp_p[0];
    float q1 = floorf(p);
    float q2 = rintf((p - q1) * 255.0f);
    q2 = fminf(fmaxf(q2, 0.0f), 255.0f);
    float wv[2] = { q1 * s + z, q2 * s + z };
#pragma unroll
    for (int k = 0; k < 2; ++k) {
      int f = 2 * i + k;
      int o = f / 1152;
      int rem = f - o * 1152;
      int c = rem / 9;
      int r = rem - c * 9;
      Wd[((r * 16 + (c >> 3)) * 256 + o) * 8 + (c & 7)] = f2bf(wv[k]);
    }
    return;
  }

  if (bx < DQ_BLK + ZB_BLK) {
    // ---- border zeroing ----
    int idx = (bx - DQ_BLK) * 256 + tid;
    if (idx >= ZB_N) return;
    int n    = idx / (16 * 452);
    int rem  = idx - n * (16 * 452);
    int oct  = rem / 452;
    int b    = rem - oct * 452;
    int h, w;
    if      (b < 114) { h = 0;           w = b; }
    else if (b < 228) { h = 113;         w = b - 114; }
    else if (b < 340) { h = b - 228 + 1; w = 0; }
    else              { h = b - 340 + 1; w = 113; }
    bhalf8 z = {0, 0, 0, 0, 0, 0, 0, 0};
    *(bhalf8*)(xp + ((size_t)(n * 16 + oct) * HP + h) * HP * 8 + (size_t)w * 8) = z;
    return;
  }

  // ---- pad transpose (interior): block = (s half-row, h, n) flattened ----
  {
    int idx = bx - (DQ_BLK + ZB_BLK);
    const int s = idx & 1;
    int rest = idx >> 1;
    const int h = rest % H_IN;
    const int n = rest / H_IN;
    const int w0 = s * 56;

#pragma unroll
    for (int k = 0; k < 7; ++k) {
      int id2 = tid + 256 * k;             // < 1792 = 128c * 14wq
      int c  = id2 / 14;
      int wq = id2 - c * 14;
      const float* src = x + (size_t)(n * 128 + c) * HW + h * W_IN + w0 + wq * 4;
      float4 v = *(const float4*)src;
      ushort4 b;
      b.x = f2bf(v.x); b.y = f2bf(v.y); b.z = f2bf(v.z); b.w = f2bf(v.w);
      *(ushort4*)&sh[c][wq * 4] = b;
    }
    __syncthreads();
    // write: 896 = 16 oct x 56 wl items; wl fastest -> 16B-contiguous stores
#pragma unroll
    for (int k = 0; k < 4; ++k) {
      int id2 = tid + 256 * k;
      if (id2 < 896) {
        int oct = id2 / 56;
        int wl  = id2 - oct * 56;
        bhalf8 v;
#pragma unroll
        for (int j = 0; j < 8; ++j) v[j] = (short)sh[oct * 8 + j][wl];
        unsigned short* dst = xp +
            ((size_t)(n * 16 + oct) * HP + (h + 1)) * HP * 8 +
            (size_t)(w0 + wl + 1) * 8;
        *(bhalf8*)dst = v;
      }
    }
  }
}

// --- fast conv (VERIFIED R14, frozen): BM=256, BN=128 px, BK=32, 8 waves,
// wave tile 64x64, 3-deep LDS pipeline, ONE phase per K-step (16 MFMA per
// barrier-pair), counted vmcnt(3), setprio, coalesced octet-plane B.

__global__ __launch_bounds__(512, 2) void conv_fast(
    const unsigned short* __restrict__ xp,   // octet-plane padded bf16
    const unsigned short* __restrict__ Wd,   // [9][16][256][8] bf16
    const float* __restrict__ bias,
    float* __restrict__ out)
{
  __shared__ unsigned short As[3 * 4 * 256 * 8];   // 3 x 16 KB (slab 8192 shorts)
  __shared__ unsigned short Bs[3 * 4 * 128 * 8];   // 3 x  8 KB (slab 4096 shorts)

  const int tid  = threadIdx.x;
  const int lane = tid & 63;
  const int wave = tid >> 6;       // 0..7
  const int wm   = wave >> 1;      // 0..3 -> 64 o each
  const int wn   = wave & 1;       // 0..1 -> 64 px each
  const int lr   = lane >> 4;      // k-quarter
  const int lc   = lane & 15;

  // bijective XCD swizzle: 1568 blocks = 8 XCDs x 196
  const int bswz = (blockIdx.x & 7) * 196 + (blockIdx.x >> 3);
  const int p0  = bswz * 128;
  const int n   = p0 / HW;         // exact: 12544 % 128 == 0
  const int hw0 = p0 - n * HW;

  // B staging: thread t <-> (oct_lo = t>>7, px = t&127); LDS = t*16B (linear).
  // Per-lane stride = 16B -> fully coalesced (1 KB contiguous per wave).
  const int pp  = tid & 127;
  const int hwp = hw0 + pp;
  const int h   = hwp / W_IN;
  const int w   = hwp - h * W_IN;
  const unsigned short* bsrc =
      xp + ((size_t)(n * 16 + (tid >> 7)) * HP + (h + 1)) * HP * 8 +
      (size_t)(w + 1) * 8;

  // A staging: thread t covers shorts t*8 of a 4096-short half-slab (+4096 2nd GLL)
  const unsigned short* asrc = Wd + tid * 8;

  // wave-uniform LDS dest bases (lane*16B added by HW)
  unsigned short* adst = As + wave * 512;
  unsigned short* bdst = Bs + wave * 512;

  // fragment read bases
  const unsigned short* arow = As + lr * 2048 + (wm * 64 + lc) * 8;
  const unsigned short* brow = Bs + lr * 1024 + (wn * 64 + lc) * 8;

  floatx4 acc[4][4];
#pragma unroll
  for (int a = 0; a < 4; ++a)
#pragma unroll
    for (int b = 0; b < 4; ++b)
      acc[a][b] = (floatx4){0.f, 0.f, 0.f, 0.f};

  auto stageA = [&](int t, int buf) {
    int r = t >> 2, q4 = t & 3;
    const unsigned short* s = asrc + (r * 16 + q4 * 4) * 2048;
    GLL16(s,        adst + buf * 8192);
    GLL16(s + 4096, adst + buf * 8192 + 4096);
  };
  auto stageB = [&](int t, int buf) {
    int r = t >> 2, q4 = t & 3;
    int dh = r / 3, dw = r - dh * 3;             // 0..2
    // wave-uniform: octet-plane step (q4*4 planes) + tap shift within plane
    ptrdiff_t off = (ptrdiff_t)(q4 * 4) * PLANE +
                    (ptrdiff_t)((dh - 1) * HP + (dw - 1)) * 8;
    GLL16(bsrc + off, bdst + buf * 4096);
  };

  // prologue: stage K-steps 0,1
  stageA(0, 0); stageB(0, 0);
  stageA(1, 1); stageB(1, 1);
  asm volatile("s_waitcnt vmcnt(3)" ::: "memory");   // step-0 tile landed
  __builtin_amdgcn_s_barrier();

  int buf = 0;
  for (int kt = 0; kt < 34; ++kt) {                  // last 2 K-steps peeled
    int sbuf = buf + 2; if (sbuf >= 3) sbuf -= 3;
    const unsigned short* ar = arow + buf * 8192;
    const unsigned short* br = brow + buf * 4096;
    bhalf8 af[4], bfv[4];

    // single phase: all frags + both stages ; 16 MFMA per barrier-pair
#pragma unroll
    for (int mi = 0; mi < 4; ++mi) af[mi] = *(const bhalf8*)(ar + mi * 128);
#pragma unroll
    for (int ni = 0; ni < 4; ++ni) bfv[ni] = *(const bhalf8*)(br + ni * 128);
    stageA(kt + 2, sbuf);
    stageB(kt + 2, sbuf);
    __builtin_amdgcn_s_barrier();
    asm volatile("s_waitcnt lgkmcnt(0)" ::: "memory");
    __builtin_amdgcn_sched_barrier(0);
    __builtin_amdgcn_s_setprio(1);
#pragma unroll
    for (int mi = 0; mi < 4; ++mi)
#pragma unroll
      for (int ni = 0; ni < 4; ++ni)
        acc[mi][ni] = __builtin_amdgcn_mfma_f32_16x16x32_bf16(
            af[mi], bfv[ni], acc[mi][ni], 0, 0, 0);
    __builtin_amdgcn_s_setprio(0);
    // counted wait: leaves only kt+2's 3 loads outstanding -> kt+1 tile complete
    asm volatile("s_waitcnt vmcnt(3)" ::: "memory");
    __builtin_amdgcn_s_barrier();

    buf = (buf + 1 == 3) ? 0 : buf + 1;
  }

  // epilogue K-steps 34,35: fully staged; drain once, no more barriers
  asm volatile("s_waitcnt vmcnt(0)" ::: "memory");
  __builtin_amdgcn_s_barrier();
#pragma unroll
  for (int kk = 0; kk < 2; ++kk) {
    int b2 = (34 + kk) % 3;
    const unsigned short* ar = arow + b2 * 8192;
    const unsigned short* br = brow + b2 * 4096;
    bhalf8 af[4], bfv[4];
#pragma unroll
    for (int mi = 0; mi < 4; ++mi) af[mi]  = *(const bhalf8*)(ar + mi * 128);
#pragma unroll
    for (int ni = 0; ni < 4; ++ni) bfv[ni] = *(const bhalf8*)(br + ni * 128);
#pragma unroll
    for (int mi = 0; mi < 4; ++mi)
#pragma unroll
      for (int ni = 0; ni < 4; ++ni)
        acc[mi][ni] = __builtin_amdgcn_mfma_f32_16x16x32_bf16(
            af[mi], bfv[ni], acc[mi][ni], 0, 0, 0);
  }

  // C-write: D col = lc (pixel), row = lr*4+j (o)
#pragma unroll
  for (int mi = 0; mi < 4; ++mi) {
#pragma unroll
    for (int j = 0; j < 4; ++j) {
      const int o  = wm * 64 + mi * 16 + lr * 4 + j;
      const float bo = bias[o];
      float* orow = out + ((size_t)(n * O_C + o)) * HW + hw0 + wn * 64;
#pragma unroll
      for (int ni = 0; ni < 4; ++ni)
        orow[ni * 16 + lc] = acc[mi][ni][j] + bo;
    }
  }
}

// ---------------- fallback (round-1, verified) ----------------

__global__ void dequant_kernel(const float* __restrict__ pw,
                               const float* __restrict__ scale_p,
                               const float* __restrict__ zp_p,
                               unsigned short* __restrict__ Wd) {
  int i = blockIdx.x * 256 + threadIdx.x;
  if (i >= (O_C * C_IN * 9) / 2) return;
  float p = pw[i];
  float s = scale_p[0], z = zp_p[0];
  float q1 = floorf(p);
  float q2 = rintf((p - q1) * 255.0f);
  q2 = fminf(fmaxf(q2, 0.0f), 255.0f);
  float wv[2] = { q1 * s + z, q2 * s + z };
#pragma unroll
  for (int k = 0; k < 2; ++k) {
    int f = 2 * i + k;
    int o = f / 1152;
    int rem = f - o * 1152;
    int c = rem / 9;
    int r = rem - c * 9;
    Wd[(r * O_C + o) * C_IN + c] = f2bf(wv[k]);
  }
}

__global__ __launch_bounds__(256, 2) void conv_kernel(
    const float* __restrict__ x,
    const unsigned short* __restrict__ Wd,
    const float* __restrict__ bias,
    float* __restrict__ out)
{
  __shared__ unsigned short As[128][32];
  __shared__ unsigned short Bs[4][128][8];
  const int tid  = threadIdx.x;
  const int lane = tid & 63;
  const int wave = tid >> 6;
  const int wm   = wave >> 1;
  const int wn   = wave & 1;
  const int p0   = blockIdx.x * 128;
  const int o0   = blockIdx.y * 128;
  const int n    = p0 / HW;
  const int hw0  = p0 - n * HW;
  const int pp = tid & 127;
  const int qh = tid >> 7;
  const int hwp = hw0 + pp;
  const int h  = hwp / W_IN;
  const int w  = hwp - h * W_IN;
  const int xnbase = n * C_IN * HW;
  const int lr = lane >> 4;
  const int lc = lane & 15;
  floatx4 acc[4][4];
#pragma unroll
  for (int a = 0; a < 4; ++a)
#pragma unroll
    for (int b = 0; b < 4; ++b)
      acc[a][b] = (floatx4){0.f, 0.f, 0.f, 0.f};
  for (int r = 0; r < 9; ++r) {
    const int dh = r / 3 - 1;
    const int dw = r % 3 - 1;
    const int ih = h + dh;
    const int iw = w + dw;
    const bool valid = ((unsigned)ih < (unsigned)H_IN) & ((unsigned)iw < (unsigned)W_IN);
    const int xb = xnbase + ih * W_IN + iw;
    const unsigned short* Wr = Wd + r * (O_C * C_IN);
    for (int c0 = 0; c0 < C_IN; c0 += 32) {
      __syncthreads();
#pragma unroll
      for (int j = 0; j < 2; ++j) {
        int sdx  = tid + 256 * j;
        int oo = sdx >> 2;
        int c8 = (sdx & 3) << 3;
        bhalf8 v = *(const bhalf8*)(Wr + (o0 + oo) * C_IN + c0 + c8);
        *(bhalf8*)(&As[oo][c8]) = v;
      }
#pragma unroll
      for (int j = 0; j < 2; ++j) {
        int q = qh + 2 * j;
        bhalf8 v;
        if (valid) {
          const float* xpp = x + xb + (c0 + (q << 3)) * HW;
#pragma unroll
          for (int i = 0; i < 8; ++i) v[i] = (short)f2bf(xpp[i * HW]);
        } else {
#pragma unroll
          for (int i = 0; i < 8; ++i) v[i] = 0;
        }
        *(bhalf8*)(&Bs[q][pp][0]) = v;
      }
      __syncthreads();
      bhalf8 af[4], bfv[4];
#pragma unroll
      for (int mi = 0; mi < 4; ++mi)
        af[mi] = *(const bhalf8*)(&As[wm * 64 + mi * 16 + lc][lr << 3]);
#pragma unroll
      for (int ni = 0; ni < 4; ++ni)
        bfv[ni] = *(const bhalf8*)(&Bs[lr][wn * 64 + ni * 16 + lc][0]);
#pragma unroll
      for (int mi = 0; mi < 4; ++mi)
#pragma unroll
        for (int ni = 0; ni < 4; ++ni)
          acc[mi][ni] = __builtin_amdgcn_mfma_f32_16x16x32_bf16(
              af[mi], bfv[ni], acc[mi][ni], 0, 0, 0);
    }
  }
#pragma unroll
  for (int mi = 0; mi < 4; ++mi) {
#pragma unroll
    for (int j = 0; j < 4; ++j) {
      const int o  = o0 + wm * 64 + mi * 16 + lr * 4 + j;
      const float bo = bias[o];
      float* orow = out + (n * O_C + o) * HW + hw0 + wn * 64;
#pragma unroll
      for (int ni = 0; ni < 4; ++ni)
        orow[ni * 16 + lc] = acc[mi][ni][j] + bo;
    }
  }
}

// ---------------- launch ----------------

extern "C" void kernel_launch(void* const* d_in, const int* in_sizes, int n_in,
                              void* d_out, int out_size, void* d_ws, size_t ws_size,
                              hipStream_t stream) {
  const float* x    = (const float*)d_in[0];
  const float* pw   = (const float*)d_in[1];
  const float* sw   = (const float*)d_in[2];
  const float* zp   = (const float*)d_in[3];
  const float* bias = (const float*)d_in[4];
  float* out = (float*)d_out;
  unsigned short* Wd = (unsigned short*)d_ws;

  if (ws_size >= WS_NEED) {
    unsigned short* xp = (unsigned short*)((char*)d_ws + XP_OFF);
    prep_all<<<dim3(PREP_BLK), dim3(256), 0, stream>>>(pw, sw, zp, x, Wd, xp);
    conv_fast<<<dim3(P_TOT / 128), dim3(512), 0, stream>>>(xp, Wd, bias, out);
  } else {
    dequant_kernel<<<dim3((O_C * C_IN * 9 / 2 + 255) / 256), dim3(256), 0, stream>>>(
        pw, sw, zp, Wd);
    dim3 grid(P_TOT / 128, O_C / 128);
    conv_kernel<<<grid, dim3(256), 0, stream>>>(x, Wd, bias, out);
  }
}